// Round 2
// baseline (423.528 us; speedup 1.0000x reference)
//
#include <hip/hip_runtime.h>
#include <hip/hip_bf16.h>
#include <math.h>

// Problem constants (from reference setup_inputs)
#define NPTS   65536
#define NGT    256
#define NCLS   80
#define TOPK   9
#define GSLICE 32     // gts per filter block
#define NPB    256    // points per filter block

// Workspace layout: [ cnt: NGT u32 (1 KB) ][ buckets: NGT * CAP u64 ]
// CAP computed from ws_size at launch (target 8192; worst gt overlaps ~6100 pts).

// Packed rank key: (sortable float bits of L) << 32 | ~point_idx
// u64-max == (higher score, then lower index) — JAX top_k tie-break.
// L = (1-0.8)*log2(sigmoid(cls)) + 0.8*log2(iou): monotone in the reference
// score sigmoid^.2 * iou^.8 (verified absmax 0.0 in round 1).
__device__ inline unsigned long long pack_key(float L, unsigned idx) {
    unsigned u   = __float_as_uint(L);
    unsigned k32 = (u & 0x80000000u) ? ~u : (u | 0x80000000u);
    return ((unsigned long long)k32 << 32) | (unsigned)(~idx);
}

// ---------------------------------------------------------------------------
// k0: zero output + per-gt counters (harness poisons both with 0xAA)
// ---------------------------------------------------------------------------
__global__ void zero_kernel(float* __restrict__ w, unsigned* __restrict__ cnt) {
    int i = blockIdx.x * 256 + threadIdx.x;
    if (i < NPTS) w[i] = 0.0f;
    if (i < NGT)  cnt[i] = 0u;
}

// ---------------------------------------------------------------------------
// k1: filter + compact. thread = point, loop over a 32-gt slice.
// Only pairs with inter > 0 (score > 0) are emitted; ~3% of all pairs.
// Hot loop is the 11-op intersection test; score+store is exec-masked.
// ---------------------------------------------------------------------------
__global__ __launch_bounds__(256) void filter_kernel(
    const float* __restrict__ cls,     // [NPTS][NCLS]
    const float* __restrict__ preds,   // [NPTS][4]
    const float* __restrict__ gtb,     // [NGT][4]
    const int*   __restrict__ glab,    // [NGT]
    unsigned*    __restrict__ cnt,     // [NGT]
    unsigned long long* __restrict__ bucket, // [NGT][cap]
    int cap)
{
    __shared__ float4 gbox[GSLICE];
    __shared__ int    glabs[GSLICE];

    const int t    = threadIdx.x;
    const int lane = t & 63;
    const int pt   = blockIdx.x * NPB + t;
    const int g0   = blockIdx.y * GSLICE;

    if (t < GSLICE) {
        gbox[t]  = ((const float4*)gtb)[g0 + t];
        glabs[t] = glab[g0 + t];
    }
    float4 pb = ((const float4*)preds)[pt];
    float parea = (pb.z - pb.x) * (pb.w - pb.y);
    __syncthreads();

    const float E1 = 1.0f - 0.8f;   // keep exact round-1 constants

    for (int gi = 0; gi < GSLICE; ++gi) {
        float4 g4 = gbox[gi];
        float ix1 = fmaxf(pb.x, g4.x), iy1 = fmaxf(pb.y, g4.y);
        float ix2 = fminf(pb.z, g4.z), iy2 = fminf(pb.w, g4.w);
        float iw  = fmaxf(ix2 - ix1, 0.0f);
        float ih  = fmaxf(iy2 - iy1, 0.0f);
        float inter = iw * ih;
        bool act = inter > 0.0f;
        unsigned long long mask = __ballot(act);
        if (mask == 0ULL) continue;
        if (act) {
            int g = g0 + gi;
            float garea = (g4.z - g4.x) * (g4.w - g4.y);
            float uni   = fmaxf(parea + garea - inter, 1e-6f);
            float iou   = inter / uni;
            float x = cls[(size_t)pt * NCLS + glabs[gi]];
            float s = 1.0f / (1.0f + expf(-x));          // same formula as round 1
            float L = E1 * log2f(s) + 0.8f * log2f(iou);
            unsigned long long key = pack_key(L, (unsigned)pt);

            // wave-level compaction: one atomicAdd per wave, coalesced store
            int rank   = __popcll(mask & ((1ULL << lane) - 1ULL));
            int nact   = __popcll(mask);
            int leader = __ffsll((unsigned long long)mask) - 1;
            int base = 0;
            if (lane == leader) base = (int)atomicAdd(&cnt[g], (unsigned)nact);
            base = __shfl(base, leader);
            int pos = base + rank;
            if (pos < cap) bucket[(size_t)g * cap + pos] = key;
        }
    }
}

// ---------------------------------------------------------------------------
// k2: per gt — top-9 over its bucket (strided register top-9 + shfl butterfly
// merge + cross-wave LDS merge), then the Gaussian weight / validity /
// atomicMax scatter (verified in round 1).
// ---------------------------------------------------------------------------
__global__ __launch_bounds__(256) void select_kernel(
    const unsigned*           __restrict__ cnt,
    const unsigned long long* __restrict__ bucket, // [NGT][cap]
    const float* __restrict__ pts,                 // [NPTS][2]
    const float* __restrict__ gtb,                 // [NGT][4]
    float* __restrict__ w,                         // [NPTS]
    int cap)
{
    const int g    = blockIdx.x;
    const int t    = threadIdx.x;
    const int lane = t & 63;
    const int wid  = t >> 6;

    __shared__ unsigned long long wl[4][TOPK];
    __shared__ unsigned tidx[TOPK];
    __shared__ float ppy[TOPK], ppx[TOPK];

    int n = (int)cnt[g];
    if (n > cap) n = cap;

    // init: 9 filler keys (score -inf, idx 0..8) guarantee 9 decodable
    // entries even if a gt has <9 overlapping points (reference fallback:
    // zero-score points at lowest indices).
    unsigned long long loc[TOPK];
#pragma unroll
    for (int k = 0; k < TOPK; ++k) loc[k] = 0ULL;
    if (t < TOPK) loc[0] = pack_key(-INFINITY, (unsigned)t);

    // strided scan of this gt's bucket, register top-9 (sorted desc)
    const unsigned long long* src = bucket + (size_t)g * cap;
    for (int i = t; i < n; i += 256) {
        unsigned long long v = src[i];
        if (v > loc[TOPK - 1]) {
            loc[TOPK - 1] = v;
#pragma unroll
            for (int j = TOPK - 1; j > 0; --j) {
                if (loc[j] > loc[j - 1]) {
                    unsigned long long tmp = loc[j];
                    loc[j] = loc[j - 1]; loc[j - 1] = tmp;
                }
            }
        }
    }
    // re-sort (loc[0] filler may be out of order if nothing displaced it)
#pragma unroll
    for (int a = 0; a < TOPK; ++a)
#pragma unroll
        for (int j = TOPK - 1; j > 0; --j)
            if (loc[j] > loc[j - 1]) {
                unsigned long long tmp = loc[j];
                loc[j] = loc[j - 1]; loc[j - 1] = tmp;
            }

    // wave butterfly merge: after 6 levels every lane has the wave's top-9
#pragma unroll
    for (int lvl = 0; lvl < 6; ++lvl) {
        const int off = 1 << lvl;
        unsigned long long oth[TOPK];
#pragma unroll
        for (int k = 0; k < TOPK; ++k) oth[k] = __shfl_xor(loc[k], off);
#pragma unroll
        for (int k = 0; k < TOPK; ++k) {
            unsigned long long v = oth[k];
            if (v > loc[TOPK - 1]) {
                loc[TOPK - 1] = v;
#pragma unroll
                for (int j = TOPK - 1; j > 0; --j) {
                    if (loc[j] > loc[j - 1]) {
                        unsigned long long tmp = loc[j];
                        loc[j] = loc[j - 1]; loc[j - 1] = tmp;
                    }
                }
            }
        }
    }

    if (lane == 0) {
#pragma unroll
        for (int k = 0; k < TOPK; ++k) wl[wid][k] = loc[k];
    }
    __syncthreads();

    if (t == 0) {
        // merge the other 3 waves' lists
#pragma unroll
        for (int wv = 1; wv < 4; ++wv) {
#pragma unroll
            for (int k = 0; k < TOPK; ++k) {
                unsigned long long v = wl[wv][k];
                if (v > loc[TOPK - 1]) {
                    loc[TOPK - 1] = v;
#pragma unroll
                    for (int j = TOPK - 1; j > 0; --j) {
                        if (loc[j] > loc[j - 1]) {
                            unsigned long long tmp = loc[j];
                            loc[j] = loc[j - 1]; loc[j - 1] = tmp;
                        }
                    }
                }
            }
        }
#pragma unroll
        for (int k = 0; k < TOPK; ++k)
            tidx[k] = ~(unsigned)(loc[k] & 0xFFFFFFFFu);
    }
    __syncthreads();

    // parallel prefetch of the 9 candidate points
    if (t < TOPK) {
        unsigned pi = tidx[t];
        ppy[t] = pts[2 * (size_t)pi];       // points col 0 ("cy" in reference)
        ppx[t] = pts[2 * (size_t)pi + 1];   // points col 1 ("cx")
    }
    __syncthreads();

    if (t == 0) {
        float4 g4 = ((const float4*)gtb)[g];
        float m0 = 0.0f, m1 = 0.0f;
#pragma unroll
        for (int k = 0; k < TOPK; ++k) { m0 += ppy[k]; m1 += ppx[k]; }
        m0 /= (float)TOPK; m1 /= (float)TOPK;

        float d0[TOPK], d1[TOPK];
        float a = 0.0f, bb = 0.0f, dd = 0.0f;
#pragma unroll
        for (int k = 0; k < TOPK; ++k) {
            d0[k] = ppy[k] - m0;
            d1[k] = ppx[k] - m1;
            a  += d0[k] * d0[k];
            bb += d0[k] * d1[k];
            dd += d1[k] * d1[k];
        }
        a /= (float)TOPK; bb /= (float)TOPK; dd /= (float)TOPK;
        float det  = a * dd - bb * bb;
        float rinv = 1.0f / (det + 1e-10f);

#pragma unroll
        for (int k = 0; k < TOPK; ++k) {
            float q = d0[k] * (dd * d0[k] - bb * d1[k])
                    + d1[k] * (a  * d1[k] - bb * d0[k]);
            float maha = q * rinv;
            float wt = expf(-0.5f * maha);
            bool valid = (ppx[k] - g4.x > 1e-10f) && (ppy[k] - g4.y > 1e-10f) &&
                         (g4.z - ppx[k] > 1e-10f) && (g4.w - ppy[k] > 1e-10f);
            float wv = valid ? wt : 0.0f;
            atomicMax((int*)&w[tidx[k]], __float_as_int(wv));
        }
    }
}

// ---------------------------------------------------------------------------
extern "C" void kernel_launch(void* const* d_in, const int* in_sizes, int n_in,
                              void* d_out, int out_size, void* d_ws, size_t ws_size,
                              hipStream_t stream) {
    const float* points  = (const float*)d_in[0];   // [65536,2]
    const float* cls     = (const float*)d_in[1];   // [65536,80]
    const float* preds   = (const float*)d_in[2];   // [65536,4]
    const float* gtb     = (const float*)d_in[3];   // [256,4]
    const int*   glab    = (const int*)d_in[4];     // [256]
    float* w = (float*)d_out;                       // [65536] f32

    unsigned*           cnt    = (unsigned*)d_ws;
    unsigned long long* bucket = (unsigned long long*)((char*)d_ws + 1024);

    // worst gt overlaps ~6100 points; cap at 8192 (16.8 MB), clamp to ws_size
    long long avail = ((long long)ws_size - 1024) / (NGT * (long long)sizeof(unsigned long long));
    int cap = (avail < 8192) ? (int)avail : 8192;

    zero_kernel<<<(NPTS + 255) / 256, 256, 0, stream>>>(w, cnt);
    filter_kernel<<<dim3(NPTS / NPB, NGT / GSLICE), 256, 0, stream>>>(
        cls, preds, gtb, glab, cnt, bucket, cap);
    select_kernel<<<NGT, 256, 0, stream>>>(cnt, bucket, points, gtb, w, cap);
}

// Round 3
// 134.146 us; speedup vs baseline: 3.1572x; 3.1572x over previous
//
#include <hip/hip_runtime.h>
#include <hip/hip_bf16.h>
#include <math.h>

// Problem constants (from reference setup_inputs)
#define NPTS   65536
#define NGT    256
#define NCLS   80
#define TOPK   9
#define GSLICE 32     // gts per filter block
#define NPB    256    // points per filter block
#define SCAP   64     // per-(block,gt) LDS staging capacity

// Workspace layout: [ cnt: NGT u32 (1 KB) ][ buckets: NGT * CAP u64 ]
// CAP computed from ws_size at launch (target 8192; worst gt overlaps ~6100 pts).

// Packed rank key: (sortable float bits of L) << 32 | ~point_idx
// u64-max == (higher score, then lower index) — JAX top_k tie-break.
// L = (1-0.8)*log2(sigmoid(cls)) + 0.8*log2(iou): monotone in the reference
// score sigmoid^.2 * iou^.8 (verified absmax 0.0 in rounds 1 & 2 — keep the
// arithmetic bit-identical).
__device__ inline unsigned long long pack_key(float L, unsigned idx) {
    unsigned u   = __float_as_uint(L);
    unsigned k32 = (u & 0x80000000u) ? ~u : (u | 0x80000000u);
    return ((unsigned long long)k32 << 32) | (unsigned)(~idx);
}

// ---------------------------------------------------------------------------
// k0: zero output + per-gt counters (harness poisons both with 0xAA)
// ---------------------------------------------------------------------------
__global__ void zero_kernel(float* __restrict__ w, unsigned* __restrict__ cnt) {
    int i = blockIdx.x * 256 + threadIdx.x;
    if (i < NPTS) w[i] = 0.0f;
    if (i < NGT)  cnt[i] = 0u;
}

// ---------------------------------------------------------------------------
// k1: filter + compact with LDS aggregation.
// thread = point, loop over a 32-gt slice. Only pairs with inter > 0
// (score > 0) are emitted (~3%). Emits go to LDS staging via LDS atomics;
// one global atomicAdd per (block, gt) reserves bucket space in the epilogue
// (round 2's per-wave global atomics — ~900K on 16 cache lines — serialized
// at L2 and cost 330 µs; this cuts them to 65K with no hot-loop dependence).
// ---------------------------------------------------------------------------
__global__ __launch_bounds__(256) void filter_kernel(
    const float* __restrict__ cls,     // [NPTS][NCLS]
    const float* __restrict__ preds,   // [NPTS][4]
    const float* __restrict__ gtb,     // [NGT][4]
    const int*   __restrict__ glab,    // [NGT]
    unsigned*    __restrict__ cnt,     // [NGT]
    unsigned long long* __restrict__ bucket, // [NGT][cap]
    int cap)
{
    __shared__ float4   gbox[GSLICE];
    __shared__ int      glabs[GSLICE];
    __shared__ float    garea[GSLICE];
    __shared__ unsigned lcnt[GSLICE];
    __shared__ unsigned gbase[GSLICE];
    __shared__ unsigned long long stage[GSLICE][SCAP]; // 16 KiB

    const int t  = threadIdx.x;
    const int pt = blockIdx.x * NPB + t;
    const int g0 = blockIdx.y * GSLICE;

    if (t < GSLICE) {
        float4 g4 = ((const float4*)gtb)[g0 + t];
        gbox[t]  = g4;
        glabs[t] = glab[g0 + t];
        garea[t] = (g4.z - g4.x) * (g4.w - g4.y);
        lcnt[t]  = 0u;
    }
    float4 pb = ((const float4*)preds)[pt];
    float parea = (pb.z - pb.x) * (pb.w - pb.y);
    __syncthreads();

    const float E1 = 1.0f - 0.8f;   // keep exact round-1 constants

    for (int gi = 0; gi < GSLICE; ++gi) {
        float4 g4 = gbox[gi];
        float ix1 = fmaxf(pb.x, g4.x), iy1 = fmaxf(pb.y, g4.y);
        float ix2 = fminf(pb.z, g4.z), iy2 = fminf(pb.w, g4.w);
        float iw  = fmaxf(ix2 - ix1, 0.0f);
        float ih  = fmaxf(iy2 - iy1, 0.0f);
        float inter = iw * ih;
        if (inter > 0.0f) {
            float uni = fmaxf(parea + garea[gi] - inter, 1e-6f);
            float iou = inter / uni;
            float x = cls[(size_t)pt * NCLS + glabs[gi]];
            float s = 1.0f / (1.0f + expf(-x));
            float L = E1 * log2f(s) + 0.8f * log2f(iou);
            unsigned long long key = pack_key(L, (unsigned)pt);

            unsigned slot = atomicAdd(&lcnt[gi], 1u);   // LDS atomic — fast
            if (slot < SCAP) {
                stage[gi][slot] = key;
            } else {
                // statistically unreachable overflow; correctness fallback
                unsigned pos = atomicAdd(&cnt[g0 + gi], 1u);
                if (pos < (unsigned)cap)
                    bucket[(size_t)(g0 + gi) * cap + pos] = key;
            }
        }
    }
    __syncthreads();

    // reserve contiguous spans: 32 global atomics per block, issued in parallel
    if (t < GSLICE) {
        unsigned c = lcnt[t];
        if (c > SCAP) c = SCAP;
        lcnt[t]  = c;
        gbase[t] = atomicAdd(&cnt[g0 + t], c);
    }
    __syncthreads();

    // coalesced copy-out of staged entries
    for (int i = t; i < GSLICE * SCAP; i += 256) {
        int gi = i >> 6;            // SCAP == 64
        int sl = i & (SCAP - 1);
        if (sl < (int)lcnt[gi]) {
            unsigned pos = gbase[gi] + (unsigned)sl;
            if (pos < (unsigned)cap)
                bucket[(size_t)(g0 + gi) * cap + pos] = stage[gi][sl];
        }
    }
}

// ---------------------------------------------------------------------------
// k2: per gt — top-9 over its bucket (strided register top-9 + shfl butterfly
// merge + cross-wave LDS merge), then the Gaussian weight / validity /
// atomicMax scatter. Verified (absmax 0.0) in rounds 1 & 2 — unchanged.
// ---------------------------------------------------------------------------
__global__ __launch_bounds__(256) void select_kernel(
    const unsigned*           __restrict__ cnt,
    const unsigned long long* __restrict__ bucket, // [NGT][cap]
    const float* __restrict__ pts,                 // [NPTS][2]
    const float* __restrict__ gtb,                 // [NGT][4]
    float* __restrict__ w,                         // [NPTS]
    int cap)
{
    const int g    = blockIdx.x;
    const int t    = threadIdx.x;
    const int lane = t & 63;
    const int wid  = t >> 6;

    __shared__ unsigned long long wl[4][TOPK];
    __shared__ unsigned tidx[TOPK];
    __shared__ float ppy[TOPK], ppx[TOPK];

    int n = (int)cnt[g];
    if (n > cap) n = cap;

    // filler keys (score -inf, idx 0..8): 9 decodable entries even if a gt
    // has <9 overlapping points (reference fallback = zero-score low indices)
    unsigned long long loc[TOPK];
#pragma unroll
    for (int k = 0; k < TOPK; ++k) loc[k] = 0ULL;
    if (t < TOPK) loc[0] = pack_key(-INFINITY, (unsigned)t);

    const unsigned long long* src = bucket + (size_t)g * cap;
    for (int i = t; i < n; i += 256) {
        unsigned long long v = src[i];
        if (v > loc[TOPK - 1]) {
            loc[TOPK - 1] = v;
#pragma unroll
            for (int j = TOPK - 1; j > 0; --j) {
                if (loc[j] > loc[j - 1]) {
                    unsigned long long tmp = loc[j];
                    loc[j] = loc[j - 1]; loc[j - 1] = tmp;
                }
            }
        }
    }
    // re-sort (loc[0] filler may be out of order if nothing displaced it)
#pragma unroll
    for (int a = 0; a < TOPK; ++a)
#pragma unroll
        for (int j = TOPK - 1; j > 0; --j)
            if (loc[j] > loc[j - 1]) {
                unsigned long long tmp = loc[j];
                loc[j] = loc[j - 1]; loc[j - 1] = tmp;
            }

    // wave butterfly merge
#pragma unroll
    for (int lvl = 0; lvl < 6; ++lvl) {
        const int off = 1 << lvl;
        unsigned long long oth[TOPK];
#pragma unroll
        for (int k = 0; k < TOPK; ++k) oth[k] = __shfl_xor(loc[k], off);
#pragma unroll
        for (int k = 0; k < TOPK; ++k) {
            unsigned long long v = oth[k];
            if (v > loc[TOPK - 1]) {
                loc[TOPK - 1] = v;
#pragma unroll
                for (int j = TOPK - 1; j > 0; --j) {
                    if (loc[j] > loc[j - 1]) {
                        unsigned long long tmp = loc[j];
                        loc[j] = loc[j - 1]; loc[j - 1] = tmp;
                    }
                }
            }
        }
    }

    if (lane == 0) {
#pragma unroll
        for (int k = 0; k < TOPK; ++k) wl[wid][k] = loc[k];
    }
    __syncthreads();

    if (t == 0) {
#pragma unroll
        for (int wv = 1; wv < 4; ++wv) {
#pragma unroll
            for (int k = 0; k < TOPK; ++k) {
                unsigned long long v = wl[wv][k];
                if (v > loc[TOPK - 1]) {
                    loc[TOPK - 1] = v;
#pragma unroll
                    for (int j = TOPK - 1; j > 0; --j) {
                        if (loc[j] > loc[j - 1]) {
                            unsigned long long tmp = loc[j];
                            loc[j] = loc[j - 1]; loc[j - 1] = tmp;
                        }
                    }
                }
            }
        }
#pragma unroll
        for (int k = 0; k < TOPK; ++k)
            tidx[k] = ~(unsigned)(loc[k] & 0xFFFFFFFFu);
    }
    __syncthreads();

    if (t < TOPK) {
        unsigned pi = tidx[t];
        ppy[t] = pts[2 * (size_t)pi];       // points col 0 ("cy" in reference)
        ppx[t] = pts[2 * (size_t)pi + 1];   // points col 1 ("cx")
    }
    __syncthreads();

    if (t == 0) {
        float4 g4 = ((const float4*)gtb)[g];
        float m0 = 0.0f, m1 = 0.0f;
#pragma unroll
        for (int k = 0; k < TOPK; ++k) { m0 += ppy[k]; m1 += ppx[k]; }
        m0 /= (float)TOPK; m1 /= (float)TOPK;

        float d0[TOPK], d1[TOPK];
        float a = 0.0f, bb = 0.0f, dd = 0.0f;
#pragma unroll
        for (int k = 0; k < TOPK; ++k) {
            d0[k] = ppy[k] - m0;
            d1[k] = ppx[k] - m1;
            a  += d0[k] * d0[k];
            bb += d0[k] * d1[k];
            dd += d1[k] * d1[k];
        }
        a /= (float)TOPK; bb /= (float)TOPK; dd /= (float)TOPK;
        float det  = a * dd - bb * bb;
        float rinv = 1.0f / (det + 1e-10f);

#pragma unroll
        for (int k = 0; k < TOPK; ++k) {
            float q = d0[k] * (dd * d0[k] - bb * d1[k])
                    + d1[k] * (a  * d1[k] - bb * d0[k]);
            float maha = q * rinv;
            float wt = expf(-0.5f * maha);
            bool valid = (ppx[k] - g4.x > 1e-10f) && (ppy[k] - g4.y > 1e-10f) &&
                         (g4.z - ppx[k] > 1e-10f) && (g4.w - ppy[k] > 1e-10f);
            float wv = valid ? wt : 0.0f;
            atomicMax((int*)&w[tidx[k]], __float_as_int(wv));
        }
    }
}

// ---------------------------------------------------------------------------
extern "C" void kernel_launch(void* const* d_in, const int* in_sizes, int n_in,
                              void* d_out, int out_size, void* d_ws, size_t ws_size,
                              hipStream_t stream) {
    const float* points  = (const float*)d_in[0];   // [65536,2]
    const float* cls     = (const float*)d_in[1];   // [65536,80]
    const float* preds   = (const float*)d_in[2];   // [65536,4]
    const float* gtb     = (const float*)d_in[3];   // [256,4]
    const int*   glab    = (const int*)d_in[4];     // [256]
    float* w = (float*)d_out;                       // [65536] f32

    unsigned*           cnt    = (unsigned*)d_ws;
    unsigned long long* bucket = (unsigned long long*)((char*)d_ws + 1024);

    // worst gt overlaps ~6100 points; cap at 8192 (16.8 MB), clamp to ws_size
    long long avail = ((long long)ws_size - 1024) / (NGT * (long long)sizeof(unsigned long long));
    int cap = (avail < 8192) ? (int)avail : 8192;

    zero_kernel<<<(NPTS + 255) / 256, 256, 0, stream>>>(w, cnt);
    filter_kernel<<<dim3(NPTS / NPB, NGT / GSLICE), 256, 0, stream>>>(
        cls, preds, gtb, glab, cnt, bucket, cap);
    select_kernel<<<NGT, 256, 0, stream>>>(cnt, bucket, points, gtb, w, cap);
}

// Round 4
// 133.391 us; speedup vs baseline: 3.1751x; 1.0057x over previous
//
#include <hip/hip_runtime.h>
#include <hip/hip_bf16.h>
#include <math.h>

// Problem constants (from reference setup_inputs)
#define NPTS   65536
#define NGT    256
#define NCLS   80
#define TOPK   9
#define GSLICE 32     // gts per filter block
#define NPB    256    // points per filter block
#define SCAP   64     // per-(block,gt) LDS staging capacity

// Workspace layout: [ cnt: NGT u32 (1 KB) ][ buckets: NGT * CAP u64 ]
// cap computed from ws_size at launch (target 8192; worst gt overlaps ~6100).
//
// Bucket entry (filter output): (iou_bits << 32) | ~point_idx.  iou is the
// bit-exact f32 the verified round-1 kernel computed; scoring is deferred.
//
// Final rank key (built in select): (sortable bits of L) << 32 | ~point_idx,
// L = 0.2*log2(sigmoid(cls)) + 0.8*log2(iou) — bit-identical to the formula
// verified absmax 0.0 in rounds 1-3. u64-max == (higher score, lower index),
// matching JAX top_k tie-break.
__device__ inline unsigned long long pack_key(float L, unsigned idx) {
    unsigned u   = __float_as_uint(L);
    unsigned k32 = (u & 0x80000000u) ? ~u : (u | 0x80000000u);
    return ((unsigned long long)k32 << 32) | (unsigned)(~idx);
}

// ---------------------------------------------------------------------------
// k0: zero output + per-gt counters (harness poisons both with 0xAA)
// ---------------------------------------------------------------------------
__global__ void zero_kernel(float* __restrict__ w, unsigned* __restrict__ cnt) {
    int i = blockIdx.x * 256 + threadIdx.x;
    if (i < NPTS) w[i] = 0.0f;
    if (i < NGT)  cnt[i] = 0u;
}

// ---------------------------------------------------------------------------
// k1: filter + compact, NO scoring. thread = point, loop over a 32-gt slice.
// Emits (iou, pt) for pairs with inter > 0 (~3%). The emit path is ~15
// instrs (round 3's version carried cls gather + expf + 2x log2f here, and
// with P(any lane active) ~ 99.8% the wave paid it every iteration — that
// was the 42 us). Wave-ballot compaction: one LDS atomic per wave-iter.
// ---------------------------------------------------------------------------
__global__ __launch_bounds__(256) void filter_kernel(
    const float* __restrict__ preds,   // [NPTS][4]
    const float* __restrict__ gtb,     // [NGT][4]
    unsigned*    __restrict__ cnt,     // [NGT]
    unsigned long long* __restrict__ bucket, // [NGT][cap]
    int cap)
{
    __shared__ float4   gbox[GSLICE];
    __shared__ float    garea[GSLICE];
    __shared__ unsigned lcnt[GSLICE];
    __shared__ unsigned gbase[GSLICE];
    __shared__ unsigned long long stage[GSLICE][SCAP]; // 16 KiB

    const int t    = threadIdx.x;
    const int lane = t & 63;
    const int pt   = blockIdx.x * NPB + t;
    const int g0   = blockIdx.y * GSLICE;

    if (t < GSLICE) {
        float4 g4 = ((const float4*)gtb)[g0 + t];
        gbox[t]  = g4;
        garea[t] = (g4.z - g4.x) * (g4.w - g4.y);
        lcnt[t]  = 0u;
    }
    float4 pb = ((const float4*)preds)[pt];
    float parea = (pb.z - pb.x) * (pb.w - pb.y);
    __syncthreads();

    for (int gi = 0; gi < GSLICE; ++gi) {
        float4 g4 = gbox[gi];
        float ix1 = fmaxf(pb.x, g4.x), iy1 = fmaxf(pb.y, g4.y);
        float ix2 = fminf(pb.z, g4.z), iy2 = fminf(pb.w, g4.w);
        float iw  = fmaxf(ix2 - ix1, 0.0f);
        float ih  = fmaxf(iy2 - iy1, 0.0f);
        float inter = iw * ih;
        bool act = inter > 0.0f;
        unsigned long long mask = __ballot(act);
        if (act) {
            // iou computed with the exact round-1 operand forms (bit-exact)
            float uni = fmaxf(parea + garea[gi] - inter, 1e-6f);
            float iou = inter / uni;
            unsigned long long entry =
                ((unsigned long long)__float_as_uint(iou) << 32) |
                (unsigned)(~(unsigned)pt);

            int rank   = __popcll(mask & ((1ULL << lane) - 1ULL));
            int nact   = __popcll(mask);
            int leader = __ffsll((unsigned long long)mask) - 1;
            unsigned base = 0;
            if (lane == leader) base = atomicAdd(&lcnt[gi], (unsigned)nact);
            base = (unsigned)__shfl((int)base, leader);
            unsigned slot = base + (unsigned)rank;
            if (slot < SCAP) {
                stage[gi][slot] = entry;
            } else {
                // statistically unreachable (per-(block,gt) count mean ~24,
                // SCAP=64 is +8 sigma); correctness fallback
                unsigned pos = atomicAdd(&cnt[g0 + gi], 1u);
                if (pos < (unsigned)cap)
                    bucket[(size_t)(g0 + gi) * cap + pos] = entry;
            }
        }
    }
    __syncthreads();

    // reserve contiguous spans: 32 global atomics per block, pipelined
    if (t < GSLICE) {
        unsigned c = lcnt[t];
        if (c > SCAP) c = SCAP;
        lcnt[t]  = c;
        gbase[t] = atomicAdd(&cnt[g0 + t], c);
    }
    __syncthreads();

    // coalesced copy-out of staged entries
    for (int i = t; i < GSLICE * SCAP; i += 256) {
        int gi = i >> 6;            // SCAP == 64
        int sl = i & (SCAP - 1);
        if (sl < (int)lcnt[gi]) {
            unsigned pos = gbase[gi] + (unsigned)sl;
            if (pos < (unsigned)cap)
                bucket[(size_t)(g0 + gi) * cap + pos] = stage[gi][sl];
        }
    }
}

// ---------------------------------------------------------------------------
// k2: per gt — score the ~n(g)~2000 survivors densely (cls gather + the
// verified L formula), top-9 (register insert + shfl butterfly + cross-wave
// merge), then the Gaussian weight / validity / atomicMax scatter (verified
// absmax 0.0 in rounds 1-3, unchanged).
// ---------------------------------------------------------------------------
__global__ __launch_bounds__(256) void select_kernel(
    const unsigned*           __restrict__ cnt,
    const unsigned long long* __restrict__ bucket, // [NGT][cap]
    const float* __restrict__ cls,                 // [NPTS][NCLS]
    const int*   __restrict__ glab,                // [NGT]
    const float* __restrict__ pts,                 // [NPTS][2]
    const float* __restrict__ gtb,                 // [NGT][4]
    float* __restrict__ w,                         // [NPTS]
    int cap)
{
    const int g    = blockIdx.x;
    const int t    = threadIdx.x;
    const int lane = t & 63;
    const int wid  = t >> 6;

    __shared__ unsigned long long wl[4][TOPK];
    __shared__ unsigned tidx[TOPK];
    __shared__ float ppy[TOPK], ppx[TOPK];

    int n = (int)cnt[g];
    if (n > cap) n = cap;
    const int lab = glab[g];
    const float E1 = 1.0f - 0.8f;   // exact round-1 constant expression

    // filler keys (score -inf, idx 0..8): 9 decodable entries even if a gt
    // has <9 overlapping points (reference fallback = zero-score low indices)
    unsigned long long loc[TOPK];
#pragma unroll
    for (int k = 0; k < TOPK; ++k) loc[k] = 0ULL;
    if (t < TOPK) loc[0] = pack_key(-INFINITY, (unsigned)t);

    const unsigned long long* src = bucket + (size_t)g * cap;

    // strip-mined x4 so the 4 cls gathers issue independently (1 block/CU in
    // this kernel -> latency must come from ILP, not TLP)
    int i = t;
    for (; i + 3 * 256 < n; i += 4 * 256) {
        unsigned long long v[4];
        float x[4];
#pragma unroll
        for (int j = 0; j < 4; ++j) v[j] = src[i + j * 256];
#pragma unroll
        for (int j = 0; j < 4; ++j) {
            unsigned p = ~(unsigned)(v[j] & 0xFFFFFFFFu);
            x[j] = cls[(size_t)p * NCLS + lab];
        }
#pragma unroll
        for (int j = 0; j < 4; ++j) {
            float iou = __uint_as_float((unsigned)(v[j] >> 32));
            float s   = 1.0f / (1.0f + expf(-x[j]));
            float L   = E1 * log2f(s) + 0.8f * log2f(iou);
            unsigned u   = __float_as_uint(L);
            unsigned k32 = (u & 0x80000000u) ? ~u : (u | 0x80000000u);
            unsigned long long key =
                ((unsigned long long)k32 << 32) | (v[j] & 0xFFFFFFFFu);
            if (key > loc[TOPK - 1]) {
                loc[TOPK - 1] = key;
#pragma unroll
                for (int jj = TOPK - 1; jj > 0; --jj)
                    if (loc[jj] > loc[jj - 1]) {
                        unsigned long long tmp = loc[jj];
                        loc[jj] = loc[jj - 1]; loc[jj - 1] = tmp;
                    }
            }
        }
    }
    for (; i < n; i += 256) {
        unsigned long long v = src[i];
        unsigned p = ~(unsigned)(v & 0xFFFFFFFFu);
        float x   = cls[(size_t)p * NCLS + lab];
        float iou = __uint_as_float((unsigned)(v >> 32));
        float s   = 1.0f / (1.0f + expf(-x));
        float L   = E1 * log2f(s) + 0.8f * log2f(iou);
        unsigned u   = __float_as_uint(L);
        unsigned k32 = (u & 0x80000000u) ? ~u : (u | 0x80000000u);
        unsigned long long key =
            ((unsigned long long)k32 << 32) | (v & 0xFFFFFFFFu);
        if (key > loc[TOPK - 1]) {
            loc[TOPK - 1] = key;
#pragma unroll
            for (int jj = TOPK - 1; jj > 0; --jj)
                if (loc[jj] > loc[jj - 1]) {
                    unsigned long long tmp = loc[jj];
                    loc[jj] = loc[jj - 1]; loc[jj - 1] = tmp;
                }
        }
    }
    // re-sort (loc[0] filler may be out of order if nothing displaced it)
#pragma unroll
    for (int a = 0; a < TOPK; ++a)
#pragma unroll
        for (int j = TOPK - 1; j > 0; --j)
            if (loc[j] > loc[j - 1]) {
                unsigned long long tmp = loc[j];
                loc[j] = loc[j - 1]; loc[j - 1] = tmp;
            }

    // wave butterfly merge: after 6 levels every lane has the wave's top-9
#pragma unroll
    for (int lvl = 0; lvl < 6; ++lvl) {
        const int off = 1 << lvl;
        unsigned long long oth[TOPK];
#pragma unroll
        for (int k = 0; k < TOPK; ++k) oth[k] = __shfl_xor(loc[k], off);
#pragma unroll
        for (int k = 0; k < TOPK; ++k) {
            unsigned long long v = oth[k];
            if (v > loc[TOPK - 1]) {
                loc[TOPK - 1] = v;
#pragma unroll
                for (int j = TOPK - 1; j > 0; --j) {
                    if (loc[j] > loc[j - 1]) {
                        unsigned long long tmp = loc[j];
                        loc[j] = loc[j - 1]; loc[j - 1] = tmp;
                    }
                }
            }
        }
    }

    if (lane == 0) {
#pragma unroll
        for (int k = 0; k < TOPK; ++k) wl[wid][k] = loc[k];
    }
    __syncthreads();

    if (t == 0) {
#pragma unroll
        for (int wv = 1; wv < 4; ++wv) {
#pragma unroll
            for (int k = 0; k < TOPK; ++k) {
                unsigned long long v = wl[wv][k];
                if (v > loc[TOPK - 1]) {
                    loc[TOPK - 1] = v;
#pragma unroll
                    for (int j = TOPK - 1; j > 0; --j) {
                        if (loc[j] > loc[j - 1]) {
                            unsigned long long tmp = loc[j];
                            loc[j] = loc[j - 1]; loc[j - 1] = tmp;
                        }
                    }
                }
            }
        }
#pragma unroll
        for (int k = 0; k < TOPK; ++k)
            tidx[k] = ~(unsigned)(loc[k] & 0xFFFFFFFFu);
    }
    __syncthreads();

    if (t < TOPK) {
        unsigned pi = tidx[t];
        ppy[t] = pts[2 * (size_t)pi];       // points col 0 ("cy" in reference)
        ppx[t] = pts[2 * (size_t)pi + 1];   // points col 1 ("cx")
    }
    __syncthreads();

    if (t == 0) {
        float4 g4 = ((const float4*)gtb)[g];
        float m0 = 0.0f, m1 = 0.0f;
#pragma unroll
        for (int k = 0; k < TOPK; ++k) { m0 += ppy[k]; m1 += ppx[k]; }
        m0 /= (float)TOPK; m1 /= (float)TOPK;

        float d0[TOPK], d1[TOPK];
        float a = 0.0f, bb = 0.0f, dd = 0.0f;
#pragma unroll
        for (int k = 0; k < TOPK; ++k) {
            d0[k] = ppy[k] - m0;
            d1[k] = ppx[k] - m1;
            a  += d0[k] * d0[k];
            bb += d0[k] * d1[k];
            dd += d1[k] * d1[k];
        }
        a /= (float)TOPK; bb /= (float)TOPK; dd /= (float)TOPK;
        float det  = a * dd - bb * bb;
        float rinv = 1.0f / (det + 1e-10f);

#pragma unroll
        for (int k = 0; k < TOPK; ++k) {
            float q = d0[k] * (dd * d0[k] - bb * d1[k])
                    + d1[k] * (a  * d1[k] - bb * d0[k]);
            float maha = q * rinv;
            float wt = expf(-0.5f * maha);
            bool valid = (ppx[k] - g4.x > 1e-10f) && (ppy[k] - g4.y > 1e-10f) &&
                         (g4.z - ppx[k] > 1e-10f) && (g4.w - ppy[k] > 1e-10f);
            float wv = valid ? wt : 0.0f;
            atomicMax((int*)&w[tidx[k]], __float_as_int(wv));
        }
    }
}

// ---------------------------------------------------------------------------
extern "C" void kernel_launch(void* const* d_in, const int* in_sizes, int n_in,
                              void* d_out, int out_size, void* d_ws, size_t ws_size,
                              hipStream_t stream) {
    const float* points  = (const float*)d_in[0];   // [65536,2]
    const float* cls     = (const float*)d_in[1];   // [65536,80]
    const float* preds   = (const float*)d_in[2];   // [65536,4]
    const float* gtb     = (const float*)d_in[3];   // [256,4]
    const int*   glab    = (const int*)d_in[4];     // [256]
    float* w = (float*)d_out;                       // [65536] f32

    unsigned*           cnt    = (unsigned*)d_ws;
    unsigned long long* bucket = (unsigned long long*)((char*)d_ws + 1024);

    // worst gt overlaps ~6100 points; cap at 8192 (16.8 MB), clamp to ws_size
    long long avail = ((long long)ws_size - 1024) / (NGT * (long long)sizeof(unsigned long long));
    int cap = (avail < 8192) ? (int)avail : 8192;

    zero_kernel<<<(NPTS + 255) / 256, 256, 0, stream>>>(w, cnt);
    filter_kernel<<<dim3(NPTS / NPB, NGT / GSLICE), 256, 0, stream>>>(
        preds, gtb, cnt, bucket, cap);
    select_kernel<<<NGT, 256, 0, stream>>>(cnt, bucket, cls, glab, points, gtb, w, cap);
}

// Round 5
// 129.374 us; speedup vs baseline: 3.2737x; 1.0311x over previous
//
#include <hip/hip_runtime.h>
#include <hip/hip_bf16.h>
#include <math.h>

// Problem constants (from reference setup_inputs)
#define NPTS   65536
#define NGT    256
#define NCLS   80
#define TOPK   9
#define GSLICE 32     // gts per filter block
#define NPB    256    // points per filter block
#define SCAP   64     // per-(block,gt) LDS staging capacity

// Workspace layout: [ cnt: NGT u32 (1 KB) ][ buckets: NGT * CAP u64 ]
// cap computed from ws_size at launch (target 8192; worst gt overlaps ~6100).
//
// Bucket entry (filter output): (iou_bits << 32) | ~point_idx.  iou is the
// bit-exact f32 the verified round-1 kernel computed; scoring is deferred to
// select, which evaluates L = 0.2*log2(sigmoid(cls)) + 0.8*log2(iou) on the
// ~500K survivors only (formula verified absmax 0.0 in rounds 1-4).
// Final rank key: (sortable bits of L) << 32 | ~point_idx; u64-max ==
// (higher score, lower index) — matches JAX top_k tie-break.
__device__ inline unsigned long long pack_key(float L, unsigned idx) {
    unsigned u   = __float_as_uint(L);
    unsigned k32 = (u & 0x80000000u) ? ~u : (u | 0x80000000u);
    return ((unsigned long long)k32 << 32) | (unsigned)(~idx);
}

// ---------------------------------------------------------------------------
// k0: zero the 256 per-gt counters (harness poisons ws with 0xAA).
// w-zeroing moved into filter_kernel (one 32-float slice per block).
// ---------------------------------------------------------------------------
__global__ void zero_cnt_kernel(unsigned* __restrict__ cnt) {
    cnt[threadIdx.x] = 0u;   // exactly NGT==256 threads
}

// ---------------------------------------------------------------------------
// k1: filter + compact, no scoring, PER-LANE LDS-atomic emit.
// Round 4's wave-ballot compaction (ballot + 2x popcll + ffsll + shfl +
// leader atomic ~12-15 instrs) was paid on 86% of all wave-iterations and
// roughly cancelled the win from removing the transcendentals. With only
// ~2 active lanes/wave, per-lane LDS atomicAdd serialization (~2 deep) is
// cheaper. Hot loop: 12-instr intersection + exec-masked ~8-instr emit.
// Each block also zeroes its 32-float slice of w (filter grid completes
// before select's atomicMax — stream order).
// ---------------------------------------------------------------------------
__global__ __launch_bounds__(256) void filter_kernel(
    const float* __restrict__ preds,   // [NPTS][4]
    const float* __restrict__ gtb,     // [NGT][4]
    unsigned*    __restrict__ cnt,     // [NGT]
    unsigned long long* __restrict__ bucket, // [NGT][cap]
    int cap,
    float* __restrict__ w)             // [NPTS]
{
    __shared__ float4   gbox[GSLICE];
    __shared__ unsigned lcnt[GSLICE];
    __shared__ unsigned gbase[GSLICE];
    __shared__ unsigned long long stage[GSLICE][SCAP]; // 16 KiB

    const int t   = threadIdx.x;
    const int pt  = blockIdx.x * NPB + t;
    const int g0  = blockIdx.y * GSLICE;
    const int bid = blockIdx.y * (NPTS / NPB) + blockIdx.x;  // 0..2047

    if (t < GSLICE) {
        gbox[t] = ((const float4*)gtb)[g0 + t];
        lcnt[t] = 0u;
    }
    // zero this block's slice of w (65536 / 2048 blocks = 32 floats)
    if (t < NPTS / (NPB / GSLICE * (NGT / GSLICE) * (NPTS / NPB) / (NPTS / NPB)) / 2048 + 32) { /* see below */ }
    if (t < 32) w[bid * 32 + t] = 0.0f;

    float4 pb = ((const float4*)preds)[pt];
    float parea = (pb.z - pb.x) * (pb.w - pb.y);
    __syncthreads();

    for (int gi = 0; gi < GSLICE; ++gi) {
        float4 g4 = gbox[gi];
        float ix1 = fmaxf(pb.x, g4.x), iy1 = fmaxf(pb.y, g4.y);
        float ix2 = fminf(pb.z, g4.z), iy2 = fminf(pb.w, g4.w);
        float iw  = fmaxf(ix2 - ix1, 0.0f);
        float ih  = fmaxf(iy2 - iy1, 0.0f);
        float inter = iw * ih;
        if (inter > 0.0f) {
            // bit-exact round-1 operand forms
            float garea = (g4.z - g4.x) * (g4.w - g4.y);
            float uni = fmaxf(parea + garea - inter, 1e-6f);
            float iou = inter / uni;
            unsigned long long entry =
                ((unsigned long long)__float_as_uint(iou) << 32) |
                (unsigned)(~(unsigned)pt);
            unsigned slot = atomicAdd(&lcnt[gi], 1u);   // LDS atomic
            if (slot < SCAP) {
                stage[gi][slot] = entry;
            } else {
                // statistically unreachable (per-(block,gt) mean ~24,
                // SCAP=64 is +8 sigma); correctness fallback
                unsigned pos = atomicAdd(&cnt[g0 + gi], 1u);
                if (pos < (unsigned)cap)
                    bucket[(size_t)(g0 + gi) * cap + pos] = entry;
            }
        }
    }
    __syncthreads();

    // reserve contiguous spans: 32 global atomics per block, pipelined
    if (t < GSLICE) {
        unsigned c = lcnt[t];
        if (c > SCAP) c = SCAP;
        lcnt[t]  = c;
        gbase[t] = atomicAdd(&cnt[g0 + t], c);
    }
    __syncthreads();

    // coalesced copy-out of staged entries
    for (int i = t; i < GSLICE * SCAP; i += 256) {
        int gi = i >> 6;            // SCAP == 64
        int sl = i & (SCAP - 1);
        if (sl < (int)lcnt[gi]) {
            unsigned pos = gbase[gi] + (unsigned)sl;
            if (pos < (unsigned)cap)
                bucket[(size_t)(g0 + gi) * cap + pos] = stage[gi][sl];
        }
    }
}

// ---------------------------------------------------------------------------
// k2: per gt — score the ~n(g) survivors densely (cls gather + verified L
// formula), top-9 (register insert + shfl butterfly + cross-wave merge),
// then Gaussian weight / validity / atomicMax scatter. Bit-identical to
// round 4 (verified absmax 0.0).
// ---------------------------------------------------------------------------
__global__ __launch_bounds__(256) void select_kernel(
    const unsigned*           __restrict__ cnt,
    const unsigned long long* __restrict__ bucket, // [NGT][cap]
    const float* __restrict__ cls,                 // [NPTS][NCLS]
    const int*   __restrict__ glab,                // [NGT]
    const float* __restrict__ pts,                 // [NPTS][2]
    const float* __restrict__ gtb,                 // [NGT][4]
    float* __restrict__ w,                         // [NPTS]
    int cap)
{
    const int g    = blockIdx.x;
    const int t    = threadIdx.x;
    const int lane = t & 63;
    const int wid  = t >> 6;

    __shared__ unsigned long long wl[4][TOPK];
    __shared__ unsigned tidx[TOPK];
    __shared__ float ppy[TOPK], ppx[TOPK];

    int n = (int)cnt[g];
    if (n > cap) n = cap;
    const int lab = glab[g];
    const float E1 = 1.0f - 0.8f;   // exact round-1 constant expression

    // filler keys (score -inf, idx 0..8): 9 decodable entries even if a gt
    // has <9 overlapping points (reference fallback = zero-score low indices)
    unsigned long long loc[TOPK];
#pragma unroll
    for (int k = 0; k < TOPK; ++k) loc[k] = 0ULL;
    if (t < TOPK) loc[0] = pack_key(-INFINITY, (unsigned)t);

    const unsigned long long* src = bucket + (size_t)g * cap;

    // strip-mined x4 so the 4 cls gathers issue independently (1 block/CU
    // -> latency hidden by ILP, not TLP)
    int i = t;
    for (; i + 3 * 256 < n; i += 4 * 256) {
        unsigned long long v[4];
        float x[4];
#pragma unroll
        for (int j = 0; j < 4; ++j) v[j] = src[i + j * 256];
#pragma unroll
        for (int j = 0; j < 4; ++j) {
            unsigned p = ~(unsigned)(v[j] & 0xFFFFFFFFu);
            x[j] = cls[(size_t)p * NCLS + lab];
        }
#pragma unroll
        for (int j = 0; j < 4; ++j) {
            float iou = __uint_as_float((unsigned)(v[j] >> 32));
            float s   = 1.0f / (1.0f + expf(-x[j]));
            float L   = E1 * log2f(s) + 0.8f * log2f(iou);
            unsigned u   = __float_as_uint(L);
            unsigned k32 = (u & 0x80000000u) ? ~u : (u | 0x80000000u);
            unsigned long long key =
                ((unsigned long long)k32 << 32) | (v[j] & 0xFFFFFFFFu);
            if (key > loc[TOPK - 1]) {
                loc[TOPK - 1] = key;
#pragma unroll
                for (int jj = TOPK - 1; jj > 0; --jj)
                    if (loc[jj] > loc[jj - 1]) {
                        unsigned long long tmp = loc[jj];
                        loc[jj] = loc[jj - 1]; loc[jj - 1] = tmp;
                    }
            }
        }
    }
    for (; i < n; i += 256) {
        unsigned long long v = src[i];
        unsigned p = ~(unsigned)(v & 0xFFFFFFFFu);
        float x   = cls[(size_t)p * NCLS + lab];
        float iou = __uint_as_float((unsigned)(v >> 32));
        float s   = 1.0f / (1.0f + expf(-x));
        float L   = E1 * log2f(s) + 0.8f * log2f(iou);
        unsigned u   = __float_as_uint(L);
        unsigned k32 = (u & 0x80000000u) ? ~u : (u | 0x80000000u);
        unsigned long long key =
            ((unsigned long long)k32 << 32) | (v & 0xFFFFFFFFu);
        if (key > loc[TOPK - 1]) {
            loc[TOPK - 1] = key;
#pragma unroll
            for (int jj = TOPK - 1; jj > 0; --jj)
                if (loc[jj] > loc[jj - 1]) {
                    unsigned long long tmp = loc[jj];
                    loc[jj] = loc[jj - 1]; loc[jj - 1] = tmp;
                }
        }
    }
    // re-sort (loc[0] filler may be out of order if nothing displaced it)
#pragma unroll
    for (int a = 0; a < TOPK; ++a)
#pragma unroll
        for (int j = TOPK - 1; j > 0; --j)
            if (loc[j] > loc[j - 1]) {
                unsigned long long tmp = loc[j];
                loc[j] = loc[j - 1]; loc[j - 1] = tmp;
            }

    // wave butterfly merge: after 6 levels every lane has the wave's top-9
#pragma unroll
    for (int lvl = 0; lvl < 6; ++lvl) {
        const int off = 1 << lvl;
        unsigned long long oth[TOPK];
#pragma unroll
        for (int k = 0; k < TOPK; ++k) oth[k] = __shfl_xor(loc[k], off);
#pragma unroll
        for (int k = 0; k < TOPK; ++k) {
            unsigned long long v = oth[k];
            if (v > loc[TOPK - 1]) {
                loc[TOPK - 1] = v;
#pragma unroll
                for (int j = TOPK - 1; j > 0; --j) {
                    if (loc[j] > loc[j - 1]) {
                        unsigned long long tmp = loc[j];
                        loc[j] = loc[j - 1]; loc[j - 1] = tmp;
                    }
                }
            }
        }
    }

    if (lane == 0) {
#pragma unroll
        for (int k = 0; k < TOPK; ++k) wl[wid][k] = loc[k];
    }
    __syncthreads();

    if (t == 0) {
#pragma unroll
        for (int wv = 1; wv < 4; ++wv) {
#pragma unroll
            for (int k = 0; k < TOPK; ++k) {
                unsigned long long v = wl[wv][k];
                if (v > loc[TOPK - 1]) {
                    loc[TOPK - 1] = v;
#pragma unroll
                    for (int j = TOPK - 1; j > 0; --j) {
                        if (loc[j] > loc[j - 1]) {
                            unsigned long long tmp = loc[j];
                            loc[j] = loc[j - 1]; loc[j - 1] = tmp;
                        }
                    }
                }
            }
        }
#pragma unroll
        for (int k = 0; k < TOPK; ++k)
            tidx[k] = ~(unsigned)(loc[k] & 0xFFFFFFFFu);
    }
    __syncthreads();

    if (t < TOPK) {
        unsigned pi = tidx[t];
        ppy[t] = pts[2 * (size_t)pi];       // points col 0 ("cy" in reference)
        ppx[t] = pts[2 * (size_t)pi + 1];   // points col 1 ("cx")
    }
    __syncthreads();

    if (t == 0) {
        float4 g4 = ((const float4*)gtb)[g];
        float m0 = 0.0f, m1 = 0.0f;
#pragma unroll
        for (int k = 0; k < TOPK; ++k) { m0 += ppy[k]; m1 += ppx[k]; }
        m0 /= (float)TOPK; m1 /= (float)TOPK;

        float d0[TOPK], d1[TOPK];
        float a = 0.0f, bb = 0.0f, dd = 0.0f;
#pragma unroll
        for (int k = 0; k < TOPK; ++k) {
            d0[k] = ppy[k] - m0;
            d1[k] = ppx[k] - m1;
            a  += d0[k] * d0[k];
            bb += d0[k] * d1[k];
            dd += d1[k] * d1[k];
        }
        a /= (float)TOPK; bb /= (float)TOPK; dd /= (float)TOPK;
        float det  = a * dd - bb * bb;
        float rinv = 1.0f / (det + 1e-10f);

#pragma unroll
        for (int k = 0; k < TOPK; ++k) {
            float q = d0[k] * (dd * d0[k] - bb * d1[k])
                    + d1[k] * (a  * d1[k] - bb * d0[k]);
            float maha = q * rinv;
            float wt = expf(-0.5f * maha);
            bool valid = (ppx[k] - g4.x > 1e-10f) && (ppy[k] - g4.y > 1e-10f) &&
                         (g4.z - ppx[k] > 1e-10f) && (g4.w - ppy[k] > 1e-10f);
            float wv = valid ? wt : 0.0f;
            atomicMax((int*)&w[tidx[k]], __float_as_int(wv));
        }
    }
}

// ---------------------------------------------------------------------------
extern "C" void kernel_launch(void* const* d_in, const int* in_sizes, int n_in,
                              void* d_out, int out_size, void* d_ws, size_t ws_size,
                              hipStream_t stream) {
    const float* points  = (const float*)d_in[0];   // [65536,2]
    const float* cls     = (const float*)d_in[1];   // [65536,80]
    const float* preds   = (const float*)d_in[2];   // [65536,4]
    const float* gtb     = (const float*)d_in[3];   // [256,4]
    const int*   glab    = (const int*)d_in[4];     // [256]
    float* w = (float*)d_out;                       // [65536] f32

    unsigned*           cnt    = (unsigned*)d_ws;
    unsigned long long* bucket = (unsigned long long*)((char*)d_ws + 1024);

    // worst gt overlaps ~6100 points; cap at 8192 (16.8 MB), clamp to ws_size
    long long avail = ((long long)ws_size - 1024) / (NGT * (long long)sizeof(unsigned long long));
    int cap = (avail < 8192) ? (int)avail : 8192;

    zero_cnt_kernel<<<1, NGT, 0, stream>>>(cnt);
    filter_kernel<<<dim3(NPTS / NPB, NGT / GSLICE), 256, 0, stream>>>(
        preds, gtb, cnt, bucket, cap, w);
    select_kernel<<<NGT, 256, 0, stream>>>(cnt, bucket, cls, glab, points, gtb, w, cap);
}